// Round 31
// baseline (76.576 us; speedup 1.0000x reference)
//
#include <hip/hip_runtime.h>

typedef short short8  __attribute__((ext_vector_type(8)));
typedef short short4v __attribute__((ext_vector_type(4)));
typedef float f32x4   __attribute__((ext_vector_type(4)));

#define NB 4
#define NS 4096
#define NE 1024
#define ND 64

__device__ __forceinline__ short f2bf(float f) {
    unsigned u = __builtin_bit_cast(unsigned, f);
    u = (u + 0x7FFFu + ((u >> 16) & 1u)) >> 16;
    return (short)u;
}
__device__ __forceinline__ float bf2f(short s) {
    unsigned u = ((unsigned)(unsigned short)s) << 16;
    return __builtin_bit_cast(float, u);
}

// LDS-only barrier (r24-validated): drains ds ops, leaves VMEM in flight.
#define LDS_BAR() do {                                               \
        asm volatile("s_waitcnt lgkmcnt(0)" ::: "memory");           \
        __builtin_amdgcn_s_barrier();                                \
        __builtin_amdgcn_sched_barrier(0);                           \
    } while (0)

// ---- kernel 1: W -> FRAGMENT-PACKED bf16 hi/lo (r18, validated) ----
__global__ void prep_wt(const float* __restrict__ WQ, const float* __restrict__ WK,
                        const float* __restrict__ WV,
                        short* __restrict__ wtp_hi, short* __restrict__ wtp_lo) {
    int idx = blockIdx.x * 256 + threadIdx.x;     // 192*1024
    if (idx >= 192 * NE) return;
    int n = idx >> 10, k = idx & (NE - 1);
    int sel = n >> 6, d = n & 63;
    const float* W = (sel == 0) ? WQ : (sel == 1 ? WK : WV);
    float v = W[k * ND + d];
    if (sel == 0) v *= 0.125f;                    // 1/sqrt(64), exact power of 2
    short hi = f2bf(v);
    short lo = f2bf(v - bf2f(hi));
    int off = ((k >> 5) * 12 + (n >> 4)) * 512 + ((k & 31) >> 3) * 128 + (n & 15) * 8 + (k & 7);
    wtp_hi[off] = hi;
    wtp_lo[off] = lo;
}

// ---- kernel 2: QKV projection — r28 validated best (UNCHANGED) ----
__global__ __launch_bounds__(256, 2) void proj_rope(
        const float* __restrict__ x,
        const short* __restrict__ wtp_hi, const short* __restrict__ wtp_lo,
        short* __restrict__ qhi, short* __restrict__ qlo,
        short* __restrict__ kfph, short* __restrict__ kfpl,
        short* __restrict__ vfp) {
    __shared__ short Xh[32 * 64], Xl[32 * 64];
    __shared__ short Vlds[64 * 32];
    const int tid = threadIdx.x;
    const int w = tid >> 6, lane = tid & 63;
    const int g = lane >> 4, cl = lane & 15;
    const int rb = blockIdx.x << 5;

    f32x4 acc[2][3];
    #pragma unroll
    for (int i = 0; i < 2; ++i)
        #pragma unroll
        for (int j = 0; j < 3; ++j) acc[i][j] = (f32x4){0.f, 0.f, 0.f, 0.f};

    const int srow = tid >> 3, skc = tid & 7;
    const float* xs0 = x + (size_t)(rb + srow) * NE + (skc << 3);
    const int swoff = srow * 64 + ((skc ^ (srow & 7)) << 3);

    const short* bph = wtp_hi + (size_t)w * 512 + (lane << 3);
    const short* bpl = wtp_lo + (size_t)w * 512 + (lane << 3);

    float4 xa0, xa1, xb0, xb1;
    short8 b0[6], b1[6];

#define LOADXA(kk) { xa0 = *(const float4*)(xs0 + (kk)); \
                     xa1 = *(const float4*)(xs0 + (kk) + 4); }
#define LOADXB(kk) { xb0 = *(const float4*)(xs0 + (kk)); \
                     xb1 = *(const float4*)(xs0 + (kk) + 4); }
#define LOADB(Bs, kk) {                                                      \
        const int ko = ((kk) >> 5) * 6144;                                   \
        _Pragma("unroll")                                                    \
        for (int ct = 0; ct < 3; ++ct) {                                     \
            Bs[ct * 2] = *(const short8*)(bph + ko + ct * 2048);             \
            if (ct < 2)                                                      \
                Bs[ct * 2 + 1] = *(const short8*)(bpl + ko + ct * 2048);     \
        } }
#define CONV(X0, X1, h8, l8) {                                               \
        float vv[8] = {X0.x, X0.y, X0.z, X0.w, X1.x, X1.y, X1.z, X1.w};      \
        _Pragma("unroll")                                                    \
        for (int q = 0; q < 8; ++q) {                                        \
            short h = f2bf(vv[q]);                                           \
            h8[q] = h;                                                       \
            l8[q] = f2bf(vv[q] - bf2f(h));                                   \
        } }
#define HALF(h, Bs) {                                                        \
        _Pragma("unroll")                                                    \
        for (int rt = 0; rt < 2; ++rt) {                                     \
            const int R = (rt << 4) + cl;                                    \
            const int ro = R * 64 + ((((h) * 4 + g) ^ (R & 7)) << 3);        \
            short8 ah = *(const short8*)(Xh + ro);                           \
            short8 al = *(const short8*)(Xl + ro);                           \
            _Pragma("unroll")                                                \
            for (int ct = 0; ct < 2; ++ct) {                                 \
                acc[rt][ct] = __builtin_amdgcn_mfma_f32_16x16x32_bf16(ah, Bs[ct*2],   acc[rt][ct], 0, 0, 0); \
                acc[rt][ct] = __builtin_amdgcn_mfma_f32_16x16x32_bf16(ah, Bs[ct*2+1], acc[rt][ct], 0, 0, 0); \
                acc[rt][ct] = __builtin_amdgcn_mfma_f32_16x16x32_bf16(al, Bs[ct*2],   acc[rt][ct], 0, 0, 0); \
            }                                                                \
            acc[rt][2] = __builtin_amdgcn_mfma_f32_16x16x32_bf16(ah, Bs[4], acc[rt][2], 0, 0, 0); \
        } }

    LOADXA(0); LOADXB(64);
    LOADB(b0, 0);

    #pragma unroll 1
    for (int k0 = 0; k0 < NE; k0 += 128) {
        {
            short8 h8, l8;
            CONV(xa0, xa1, h8, l8);
            LDS_BAR();
            *(short8*)(Xh + swoff) = h8;
            *(short8*)(Xl + swoff) = l8;
            if (k0 + 128 < NE) LOADXA(k0 + 128);
            LOADB(b1, k0 + 32);
            LDS_BAR();
            HALF(0, b0);
            LOADB(b0, k0 + 64);
            HALF(1, b1);
        }
        {
            short8 h8, l8;
            CONV(xb0, xb1, h8, l8);
            LDS_BAR();
            *(short8*)(Xh + swoff) = h8;
            *(short8*)(Xl + swoff) = l8;
            if (k0 + 192 < NE) LOADXB(k0 + 192);
            LOADB(b1, k0 + 96);
            LDS_BAR();
            HALF(0, b0);
            if (k0 + 128 < NE) LOADB(b0, k0 + 128);
            HALF(1, b1);
        }
    }
#undef LOADXA
#undef LOADXB
#undef LOADB
#undef CONV
#undef HALF

    __syncthreads();

    #pragma unroll
    for (int rt = 0; rt < 2; ++rt) {
        #pragma unroll
        for (int ct = 0; ct < 3; ++ct) {
            int c = ((w + (ct << 2)) << 4) + cl;
            #pragma unroll
            for (int r = 0; r < 4; ++r) {
                int row = rb + (rt << 4) + (g << 2) + r;
                int sl = row & 31;
                float val = acc[rt][ct][r];
                if (c < 128) {
                    int d = c & 63;
                    int p = d >> 1;
                    float freq = exp2f(-(float)p * 0.41524101186091903f);
                    float theta = (float)(row & (NS - 1)) * freq;
                    float sn = sinf(theta), cs = cosf(theta);
                    float partner = __shfl_xor(val, 1);
                    float rot = (c & 1) ? fmaf(partner, sn, val * cs)
                                        : fmaf(-partner, sn, val * cs);
                    short hi = f2bf(rot);
                    short lo = f2bf(rot - bf2f(hi));
                    if (c < 64) {
                        int off = row * ND + d;
                        qhi[off] = hi; qlo[off] = lo;
                    } else {
                        Xh[sl * 64 + d] = hi;
                        Xl[sl * 64 + d] = lo;
                    }
                } else {
                    Vlds[(c - 128) * 32 + sl] = f2bf(val);
                }
            }
        }
    }
    __syncthreads();

    {
        const size_t tbase = ((size_t)((rb >> 12) << 7) + ((rb & (NS - 1)) >> 5)) * 2048;
        {
            const int ci = (tid >> 7) & 1, hf = (tid >> 6) & 1, ln = tid & 63;
            const int src = (ci * 16 + (ln & 15)) * 64 + hf * 32 + (ln >> 4) * 8;
            *(short8*)(kfph + tbase + tid * 8) = *(const short8*)(Xh + src);
            *(short8*)(kfpl + tbase + tid * 8) = *(const short8*)(Xl + src);
        }
        if (tid < 256) {
            const int dt = (tid >> 6) & 3, ln = tid & 63;
            const int src = (dt * 16 + (ln & 15)) * 32 + (ln >> 4) * 8;
            *(short8*)(vfp + tbase + tid * 8) = *(const short8*)(Vlds + src);
        }
    }
}

// ---- kernel 3: causal flash attention — R31: KVBLK 32 -> 64 (softmax + Ps
//      round-trip amortized 2x; same math) + T5 setprio around MFMA clusters.
//      launch_bounds(256,3): VGPR cap ~168 for kf[4][4]+vf[8] without spill. ----
__global__ __launch_bounds__(256, 3) void attn_fused(
        const short* __restrict__ qhi, const short* __restrict__ qlo,
        const short* __restrict__ kfph, const short* __restrict__ kfpl,
        const short* __restrict__ vfp, float* __restrict__ outp) {
    __shared__ short Ps[4][16][72];
    __shared__ float Co[4][16][66];
    __shared__ float Cm[4][16], Cls[4][16];
    const int tid = threadIdx.x;
    const int lane = tid & 63, w = tid >> 6;
    const int g = lane >> 4, cl = lane & 15;
    const int bid = blockIdx.x;
    const int b = (bid >> 1) & 3;
    const int t = 255 - (((bid >> 3) << 1) | (bid & 1));   // heavy tiles first
    const int qw = t << 4;
    const int rowb = b << 12;

    short8 qh[2], ql[2];
    #pragma unroll
    for (int ks = 0; ks < 2; ++ks) {
        int off = ((rowb + qw + cl) << 6) + (ks << 5) + (g << 3);
        qh[ks] = *(const short8*)(qhi + off);
        ql[ks] = *(const short8*)(qlo + off);
    }

    f32x4 o[4];
    #pragma unroll
    for (int i = 0; i < 4; ++i) o[i] = (f32x4){0.f, 0.f, 0.f, 0.f};
    float m = -1e38f, lsp = 0.f;

    const int nkv = (t >> 2) + 1;                 // 64-wide kv tiles
    const short* kbaseh = kfph + (size_t)(b << 7) * 2048 + (lane << 3);
    const short* kbasel = kfpl + (size_t)(b << 7) * 2048 + (lane << 3);
    const short* vbase  = vfp  + (size_t)(b << 7) * 2048 + (lane << 3);

    short8 kf[4][4];   // [ci 0..3 over 64 kv][kh0,kh1,kl0,kl1]
    short8 vf[8];      // [ks*4 + dt]

#define LOADK(jj) {                                                          \
        _Pragma("unroll")                                                    \
        for (int ci = 0; ci < 4; ++ci) {                                     \
            const short* kh = kbaseh + (jj) * 4096 + ci * 1024;              \
            const short* kl = kbasel + (jj) * 4096 + ci * 1024;              \
            kf[ci][0] = *(const short8*)(kh);                                \
            kf[ci][1] = *(const short8*)(kh + 512);                          \
            kf[ci][2] = *(const short8*)(kl);                                \
            kf[ci][3] = *(const short8*)(kl + 512);                          \
        } }
#define LOADV(jj) {                                                          \
        _Pragma("unroll")                                                    \
        for (int ks = 0; ks < 2; ++ks)                                       \
            _Pragma("unroll")                                                \
            for (int dt = 0; dt < 4; ++dt)                                   \
                vf[ks * 4 + dt] = *(const short8*)(vbase + (jj) * 4096       \
                                                   + ks * 2048 + dt * 512);  \
        }

    if (w < nkv) {
        LOADK(w); LOADV(w);
        #pragma unroll 1
        for (int j = w; j < nkv; j += 4) {
            const int kv0 = j << 6;
            // QK^T (swapped operands): sc[ci][r] = S[kv=kv0+(ci<<4)+(g<<2)+r][q=cl]
            f32x4 sc[4];
            __builtin_amdgcn_s_setprio(1);
            #pragma unroll
            for (int ci = 0; ci < 4; ++ci) {
                f32x4 s = (f32x4){0.f, 0.f, 0.f, 0.f};
                s = __builtin_amdgcn_mfma_f32_16x16x32_bf16(kf[ci][0], qh[0], s, 0, 0, 0);
                s = __builtin_amdgcn_mfma_f32_16x16x32_bf16(kf[ci][1], qh[1], s, 0, 0, 0);
                s = __builtin_amdgcn_mfma_f32_16x16x32_bf16(kf[ci][0], ql[0], s, 0, 0, 0);
                s = __builtin_amdgcn_mfma_f32_16x16x32_bf16(kf[ci][1], ql[1], s, 0, 0, 0);
                s = __builtin_amdgcn_mfma_f32_16x16x32_bf16(kf[ci][2], qh[0], s, 0, 0, 0);
                s = __builtin_amdgcn_mfma_f32_16x16x32_bf16(kf[ci][3], qh[1], s, 0, 0, 0);
                sc[ci] = s;
            }
            __builtin_amdgcn_s_setprio(0);
            const int jn = j + 4;
            if (jn < nkv) LOADK(jn);              // refill K frags (consumed above)

            if (j == nkv - 1) {
                #pragma unroll
                for (int ci = 0; ci < 4; ++ci)
                    #pragma unroll
                    for (int r = 0; r < 4; ++r)
                        if (kv0 + (ci << 4) + (g << 2) + r > qw + cl) sc[ci][r] = -1e30f;
            }
            // lane-local softmax (row q=cl): 16-per-lane tree + 2 cross-g shfls
            float pm = fmaxf(fmaxf(fmaxf(sc[0][0], sc[0][1]), fmaxf(sc[0][2], sc[0][3])),
                             fmaxf(fmaxf(sc[1][0], sc[1][1]), fmaxf(sc[1][2], sc[1][3])));
            float pm2 = fmaxf(fmaxf(fmaxf(sc[2][0], sc[2][1]), fmaxf(sc[2][2], sc[2][3])),
                              fmaxf(fmaxf(sc[3][0], sc[3][1]), fmaxf(sc[3][2], sc[3][3])));
            pm = fmaxf(pm, pm2);
            pm = fmaxf(pm, __shfl_xor(pm, 16));
            pm = fmaxf(pm, __shfl_xor(pm, 32));
            const float mo = m;
            m = fmaxf(m, pm);
            const float rs = __expf(mo - m);
            float psum = 0.f;
            #pragma unroll
            for (int ci = 0; ci < 4; ++ci) {
                float p0 = __expf(sc[ci][0] - m), p1 = __expf(sc[ci][1] - m);
                float p2 = __expf(sc[ci][2] - m), p3 = __expf(sc[ci][3] - m);
                psum += (p0 + p1) + (p2 + p3);
                short4v pk;
                pk[0] = f2bf(p0); pk[1] = f2bf(p1); pk[2] = f2bf(p2); pk[3] = f2bf(p3);
                *(short4v*)(&Ps[w][cl][(ci << 4) + (g << 2)]) = pk;
            }
            lsp = lsp * rs + psum;
            if (__any(m > mo)) {
                float rs4[4];
                #pragma unroll
                for (int r = 0; r < 4; ++r) rs4[r] = __shfl(rs, (g << 2) + r);
                #pragma unroll
                for (int dt = 0; dt < 4; ++dt)
                    #pragma unroll
                    for (int r = 0; r < 4; ++r) o[dt][r] *= rs4[r];
            }
            // PV: 2 k-slices x 4 d-tiles, V frags direct from registers
            __builtin_amdgcn_s_setprio(1);
            #pragma unroll
            for (int ks = 0; ks < 2; ++ks) {
                short8 pa = *(short8*)(&Ps[w][cl][(ks << 5) + (g << 3)]);
                #pragma unroll
                for (int dt = 0; dt < 4; ++dt)
                    o[dt] = __builtin_amdgcn_mfma_f32_16x16x32_bf16(pa, vf[ks * 4 + dt], o[dt], 0, 0, 0);
            }
            __builtin_amdgcn_s_setprio(0);
            if (jn < nkv) LOADV(jn);              // refill V frags (consumed above)
        }
    }
#undef LOADK
#undef LOADV

    // publish partials (idle waves: m=-1e38, lsp=0 -> zero weight)
    lsp += __shfl_xor(lsp, 16);
    lsp += __shfl_xor(lsp, 32);
    if (g == 0) { Cm[w][cl] = m; Cls[w][cl] = lsp; }
    #pragma unroll
    for (int dt = 0; dt < 4; ++dt)
        #pragma unroll
        for (int r = 0; r < 4; ++r)
            Co[w][(g << 2) + r][(dt << 4) + cl] = o[dt][r];
    __syncthreads();

    // exact flash-combine by wave 0
    if (w == 0) {
        #pragma unroll
        for (int r = 0; r < 4; ++r) {
            const int row = (g << 2) + r;
            float M = fmaxf(fmaxf(Cm[0][row], Cm[1][row]), fmaxf(Cm[2][row], Cm[3][row]));
            float e0 = __expf(Cm[0][row] - M), e1 = __expf(Cm[1][row] - M);
            float e2 = __expf(Cm[2][row] - M), e3 = __expf(Cm[3][row] - M);
            float L = Cls[0][row] * e0 + Cls[1][row] * e1 + Cls[2][row] * e2 + Cls[3][row] * e3;
            float inv = 1.f / L;
            #pragma unroll
            for (int dt = 0; dt < 4; ++dt) {
                int d = (dt << 4) + cl;
                float O = Co[0][row][d] * e0 + Co[1][row][d] * e1
                        + Co[2][row][d] * e2 + Co[3][row][d] * e3;
                outp[(rowb + qw + row) * ND + d] = O * inv;
            }
        }
    }
}

extern "C" void kernel_launch(void* const* d_in, const int* in_sizes, int n_in,
                              void* d_out, int out_size, void* d_ws, size_t ws_size,
                              hipStream_t stream) {
    const float* x  = (const float*)d_in[0];
    // d_in[1] = mask (int32 tril) -- causal structure known, unused
    const float* WQ = (const float*)d_in[2];
    const float* WK = (const float*)d_in[3];
    const float* WV = (const float*)d_in[4];

    const size_t need = 786432u + 5u * 2097152u;   // 11,272,192 B (proven available)
    if (ws_size < need) return;

    char* ws = (char*)d_ws;
    short* wtph = (short*)(ws);                                  // packed B frags, 384 KB
    short* wtpl = (short*)(ws + 393216);
    short* qhi  = (short*)(ws + 786432);                         // 2 MB each
    short* qlo  = (short*)(ws + 786432 + 1 * 2097152);
    short* kfph = (short*)(ws + 786432 + 2 * 2097152);           // K frag-packed hi
    short* kfpl = (short*)(ws + 786432 + 3 * 2097152);           // K frag-packed lo
    short* vfp  = (short*)(ws + 786432 + 4 * 2097152);           // V frag-packed

    prep_wt<<<768, 256, 0, stream>>>(WQ, WK, WV, wtph, wtpl);
    proj_rope<<<512, 256, 0, stream>>>(x, wtph, wtpl, qhi, qlo, kfph, kfpl, vfp);
    attn_fused<<<1024, 256, 0, stream>>>(qhi, qlo, kfph, kfpl, vfp, (float*)d_out);
}

// Round 32
// 72.698 us; speedup vs baseline: 1.0533x; 1.0533x over previous
//
#include <hip/hip_runtime.h>

typedef short short8  __attribute__((ext_vector_type(8)));
typedef short short4v __attribute__((ext_vector_type(4)));
typedef float f32x4   __attribute__((ext_vector_type(4)));

#define NB 4
#define NS 4096
#define NE 1024
#define ND 64

__device__ __forceinline__ short f2bf(float f) {
    unsigned u = __builtin_bit_cast(unsigned, f);
    u = (u + 0x7FFFu + ((u >> 16) & 1u)) >> 16;
    return (short)u;
}
__device__ __forceinline__ float bf2f(short s) {
    unsigned u = ((unsigned)(unsigned short)s) << 16;
    return __builtin_bit_cast(float, u);
}

// LDS-only barrier (r24-validated): drains ds ops, leaves VMEM in flight.
#define LDS_BAR() do {                                               \
        asm volatile("s_waitcnt lgkmcnt(0)" ::: "memory");           \
        __builtin_amdgcn_s_barrier();                                \
        __builtin_amdgcn_sched_barrier(0);                           \
    } while (0)

// ---- kernel 1: W -> FRAGMENT-PACKED bf16 hi/lo (r18, validated) ----
__global__ void prep_wt(const float* __restrict__ WQ, const float* __restrict__ WK,
                        const float* __restrict__ WV,
                        short* __restrict__ wtp_hi, short* __restrict__ wtp_lo) {
    int idx = blockIdx.x * 256 + threadIdx.x;     // 192*1024
    if (idx >= 192 * NE) return;
    int n = idx >> 10, k = idx & (NE - 1);
    int sel = n >> 6, d = n & 63;
    const float* W = (sel == 0) ? WQ : (sel == 1 ? WK : WV);
    float v = W[k * ND + d];
    if (sel == 0) v *= 0.125f;                    // 1/sqrt(64), exact power of 2
    short hi = f2bf(v);
    short lo = f2bf(v - bf2f(hi));
    int off = ((k >> 5) * 12 + (n >> 4)) * 512 + ((k & 31) >> 3) * 128 + (n & 15) * 8 + (k & 7);
    wtp_hi[off] = hi;
    wtp_lo[off] = lo;
}

// ---- kernel 2: QKV projection — r28 validated best (43.6us):
//      split-bf16 MFMA, packed-B coalesced loads, balanced col-tile remap
//      (wave w owns tiles {w, w+4, w+8}; ct==2 = V tile, single-term bf16),
//      LDS-only barriers, x 2-slot ping-pong, frag-pack epilogue. ----
__global__ __launch_bounds__(256, 2) void proj_rope(
        const float* __restrict__ x,
        const short* __restrict__ wtp_hi, const short* __restrict__ wtp_lo,
        short* __restrict__ qhi, short* __restrict__ qlo,
        short* __restrict__ kfph, short* __restrict__ kfpl,
        short* __restrict__ vfp) {
    __shared__ short Xh[32 * 64], Xl[32 * 64];    // loop: x stage; epilogue: K hi/lo
    __shared__ short Vlds[64 * 32];               // epilogue: V (d-major [d][s])
    const int tid = threadIdx.x;
    const int w = tid >> 6, lane = tid & 63;
    const int g = lane >> 4, cl = lane & 15;
    const int rb = blockIdx.x << 5;               // 32-row tile

    f32x4 acc[2][3];
    #pragma unroll
    for (int i = 0; i < 2; ++i)
        #pragma unroll
        for (int j = 0; j < 3; ++j) acc[i][j] = (f32x4){0.f, 0.f, 0.f, 0.f};

    const int srow = tid >> 3, skc = tid & 7;
    const float* xs0 = x + (size_t)(rb + srow) * NE + (skc << 3);
    const int swoff = srow * 64 + ((skc ^ (srow & 7)) << 3);

    const short* bph = wtp_hi + (size_t)w * 512 + (lane << 3);   // tile w; + ct*2048 per ct
    const short* bpl = wtp_lo + (size_t)w * 512 + (lane << 3);

    float4 xa0, xa1, xb0, xb1;    // 2-slot x ping-pong
    short8 b0[6], b1[6];

#define LOADXA(kk) { xa0 = *(const float4*)(xs0 + (kk)); \
                     xa1 = *(const float4*)(xs0 + (kk) + 4); }
#define LOADXB(kk) { xb0 = *(const float4*)(xs0 + (kk)); \
                     xb1 = *(const float4*)(xs0 + (kk) + 4); }
#define LOADB(Bs, kk) {                                                      \
        const int ko = ((kk) >> 5) * 6144;                                   \
        _Pragma("unroll")                                                    \
        for (int ct = 0; ct < 3; ++ct) {                                     \
            Bs[ct * 2] = *(const short8*)(bph + ko + ct * 2048);             \
            if (ct < 2)                                                      \
                Bs[ct * 2 + 1] = *(const short8*)(bpl + ko + ct * 2048);     \
        } }
#define CONV(X0, X1, h8, l8) {                                               \
        float vv[8] = {X0.x, X0.y, X0.z, X0.w, X1.x, X1.y, X1.z, X1.w};      \
        _Pragma("unroll")                                                    \
        for (int q = 0; q < 8; ++q) {                                        \
            short h = f2bf(vv[q]);                                           \
            h8[q] = h;                                                       \
            l8[q] = f2bf(vv[q] - bf2f(h));                                   \
        } }
#define HALF(h, Bs) {                                                        \
        _Pragma("unroll")                                                    \
        for (int rt = 0; rt < 2; ++rt) {                                     \
            const int R = (rt << 4) + cl;                                    \
            const int ro = R * 64 + ((((h) * 4 + g) ^ (R & 7)) << 3);        \
            short8 ah = *(const short8*)(Xh + ro);                           \
            short8 al = *(const short8*)(Xl + ro);                           \
            _Pragma("unroll")                                                \
            for (int ct = 0; ct < 2; ++ct) {                                 \
                acc[rt][ct] = __builtin_amdgcn_mfma_f32_16x16x32_bf16(ah, Bs[ct*2],   acc[rt][ct], 0, 0, 0); \
                acc[rt][ct] = __builtin_amdgcn_mfma_f32_16x16x32_bf16(ah, Bs[ct*2+1], acc[rt][ct], 0, 0, 0); \
                acc[rt][ct] = __builtin_amdgcn_mfma_f32_16x16x32_bf16(al, Bs[ct*2],   acc[rt][ct], 0, 0, 0); \
            }                                                                \
            acc[rt][2] = __builtin_amdgcn_mfma_f32_16x16x32_bf16(ah, Bs[4], acc[rt][2], 0, 0, 0); \
        } }

    LOADXA(0); LOADXB(64);
    LOADB(b0, 0);

    #pragma unroll 1
    for (int k0 = 0; k0 < NE; k0 += 128) {
        {
            short8 h8, l8;
            CONV(xa0, xa1, h8, l8);
            LDS_BAR();
            *(short8*)(Xh + swoff) = h8;
            *(short8*)(Xl + swoff) = l8;
            if (k0 + 128 < NE) LOADXA(k0 + 128);
            LOADB(b1, k0 + 32);
            LDS_BAR();
            HALF(0, b0);
            LOADB(b0, k0 + 64);
            HALF(1, b1);
        }
        {
            short8 h8, l8;
            CONV(xb0, xb1, h8, l8);
            LDS_BAR();
            *(short8*)(Xh + swoff) = h8;
            *(short8*)(Xl + swoff) = l8;
            if (k0 + 192 < NE) LOADXB(k0 + 192);
            LOADB(b1, k0 + 96);
            LDS_BAR();
            HALF(0, b0);
            if (k0 + 128 < NE) LOADB(b0, k0 + 128);
            HALF(1, b1);
        }
    }
#undef LOADXA
#undef LOADXB
#undef LOADB
#undef CONV
#undef HALF

    // ---- epilogue ----
    __syncthreads();

    // phase 1: RoPE + route. Q -> direct; K -> Xh/Xl[(s&31)][d]; V -> Vlds[d][s&31].
    #pragma unroll
    for (int rt = 0; rt < 2; ++rt) {
        #pragma unroll
        for (int ct = 0; ct < 3; ++ct) {
            int c = ((w + (ct << 2)) << 4) + cl;   // balanced remapped columns
            #pragma unroll
            for (int r = 0; r < 4; ++r) {
                int row = rb + (rt << 4) + (g << 2) + r;
                int sl = row & 31;
                float val = acc[rt][ct][r];
                if (c < 128) {
                    int d = c & 63;
                    int p = d >> 1;
                    float freq = exp2f(-(float)p * 0.41524101186091903f);
                    float theta = (float)(row & (NS - 1)) * freq;
                    float sn = sinf(theta), cs = cosf(theta);
                    float partner = __shfl_xor(val, 1);
                    float rot = (c & 1) ? fmaf(partner, sn, val * cs)
                                        : fmaf(-partner, sn, val * cs);
                    short hi = f2bf(rot);
                    short lo = f2bf(rot - bf2f(hi));
                    if (c < 64) {
                        int off = row * ND + d;
                        qhi[off] = hi; qlo[off] = lo;
                    } else {
                        Xh[sl * 64 + d] = hi;
                        Xl[sl * 64 + d] = lo;
                    }
                } else {
                    Vlds[(c - 128) * 32 + sl] = f2bf(val);
                }
            }
        }
    }
    __syncthreads();

    // phase 2: coalesced frag-pack stores — one 16B chunk/thread/buffer (r22, validated)
    {
        const size_t tbase = ((size_t)((rb >> 12) << 7) + ((rb & (NS - 1)) >> 5)) * 2048;
        {
            const int ci = (tid >> 7) & 1, hf = (tid >> 6) & 1, ln = tid & 63;
            const int src = (ci * 16 + (ln & 15)) * 64 + hf * 32 + (ln >> 4) * 8;
            *(short8*)(kfph + tbase + tid * 8) = *(const short8*)(Xh + src);
            *(short8*)(kfpl + tbase + tid * 8) = *(const short8*)(Xl + src);
        }
        if (tid < 256) {
            const int dt = (tid >> 6) & 3, ln = tid & 63;
            const int src = (dt * 16 + (ln & 15)) * 32 + (ln >> 4) * 8;
            *(short8*)(vfp + tbase + tid * 8) = *(const short8*)(Vlds + src);
        }
    }
}

// ---- kernel 3: causal flash attention — validated (~27us): barrier-free KV-split,
//      frag-packed K/V coalesced loads, lane-local softmax, XCD-pinned batches. ----
__global__ __launch_bounds__(256, 4) void attn_fused(
        const short* __restrict__ qhi, const short* __restrict__ qlo,
        const short* __restrict__ kfph, const short* __restrict__ kfpl,
        const short* __restrict__ vfp, float* __restrict__ outp) {
    __shared__ short Ps[4][16][40];
    __shared__ float Co[4][16][66];
    __shared__ float Cm[4][16], Cls[4][16];
    const int tid = threadIdx.x;
    const int lane = tid & 63, w = tid >> 6;
    const int g = lane >> 4, cl = lane & 15;
    const int bid = blockIdx.x;
    const int b = (bid >> 1) & 3;
    const int t = 255 - (((bid >> 3) << 1) | (bid & 1));   // heavy tiles first
    const int qw = t << 4;
    const int rowb = b << 12;

    short8 qh[2], ql[2];
    #pragma unroll
    for (int ks = 0; ks < 2; ++ks) {
        int off = ((rowb + qw + cl) << 6) + (ks << 5) + (g << 3);
        qh[ks] = *(const short8*)(qhi + off);
        ql[ks] = *(const short8*)(qlo + off);
    }

    f32x4 o[4];
    #pragma unroll
    for (int i = 0; i < 4; ++i) o[i] = (f32x4){0.f, 0.f, 0.f, 0.f};
    float m = -1e38f, lsp = 0.f;

    const int nkv = (t >> 1) + 1;                 // 32-wide kv tiles
    const short* kbaseh = kfph + (size_t)(b << 7) * 2048 + (lane << 3);
    const short* kbasel = kfpl + (size_t)(b << 7) * 2048 + (lane << 3);
    const short* vbase  = vfp  + (size_t)(b << 7) * 2048 + (lane << 3);

    short8 kf[2][4];
    short8 vf[4];

#define LOADK(jj) {                                                          \
        _Pragma("unroll")                                                    \
        for (int ci = 0; ci < 2; ++ci) {                                     \
            const short* kh = kbaseh + (jj) * 2048 + ci * 1024;              \
            const short* kl = kbasel + (jj) * 2048 + ci * 1024;              \
            kf[ci][0] = *(const short8*)(kh);                                \
            kf[ci][1] = *(const short8*)(kh + 512);                          \
            kf[ci][2] = *(const short8*)(kl);                                \
            kf[ci][3] = *(const short8*)(kl + 512);                          \
        } }
#define LOADV(jj) {                                                          \
        _Pragma("unroll")                                                    \
        for (int dt = 0; dt < 4; ++dt)                                       \
            vf[dt] = *(const short8*)(vbase + (jj) * 2048 + dt * 512);       \
        }

    if (w < nkv) {
        LOADK(w); LOADV(w);
        #pragma unroll 1
        for (int j = w; j < nkv; j += 4) {
            f32x4 sc[2];
            #pragma unroll
            for (int ci = 0; ci < 2; ++ci) {
                f32x4 s = (f32x4){0.f, 0.f, 0.f, 0.f};
                s = __builtin_amdgcn_mfma_f32_16x16x32_bf16(kf[ci][0], qh[0], s, 0, 0, 0);
                s = __builtin_amdgcn_mfma_f32_16x16x32_bf16(kf[ci][1], qh[1], s, 0, 0, 0);
                s = __builtin_amdgcn_mfma_f32_16x16x32_bf16(kf[ci][0], ql[0], s, 0, 0, 0);
                s = __builtin_amdgcn_mfma_f32_16x16x32_bf16(kf[ci][1], ql[1], s, 0, 0, 0);
                s = __builtin_amdgcn_mfma_f32_16x16x32_bf16(kf[ci][2], qh[0], s, 0, 0, 0);
                s = __builtin_amdgcn_mfma_f32_16x16x32_bf16(kf[ci][3], qh[1], s, 0, 0, 0);
                sc[ci] = s;
            }
            const int jn = j + 4;
            if (jn < nkv) LOADK(jn);

            if (j == nkv - 1) {
                #pragma unroll
                for (int ci = 0; ci < 2; ++ci)
                    #pragma unroll
                    for (int r = 0; r < 4; ++r)
                        if ((j << 5) + (ci << 4) + (g << 2) + r > qw + cl) sc[ci][r] = -1e30f;
            }
            float pm = fmaxf(fmaxf(fmaxf(sc[0][0], sc[0][1]), fmaxf(sc[0][2], sc[0][3])),
                             fmaxf(fmaxf(sc[1][0], sc[1][1]), fmaxf(sc[1][2], sc[1][3])));
            pm = fmaxf(pm, __shfl_xor(pm, 16));
            pm = fmaxf(pm, __shfl_xor(pm, 32));
            const float mo = m;
            m = fmaxf(m, pm);
            const float rs = __expf(mo - m);
            float psum = 0.f;
            #pragma unroll
            for (int ci = 0; ci < 2; ++ci) {
                float p0 = __expf(sc[ci][0] - m), p1 = __expf(sc[ci][1] - m);
                float p2 = __expf(sc[ci][2] - m), p3 = __expf(sc[ci][3] - m);
                psum += (p0 + p1) + (p2 + p3);
                short4v pk;
                pk[0] = f2bf(p0); pk[1] = f2bf(p1); pk[2] = f2bf(p2); pk[3] = f2bf(p3);
                *(short4v*)(&Ps[w][cl][(ci << 4) + (g << 2)]) = pk;
            }
            lsp = lsp * rs + psum;
            if (__any(m > mo)) {
                float rs4[4];
                #pragma unroll
                for (int r = 0; r < 4; ++r) rs4[r] = __shfl(rs, (g << 2) + r);
                #pragma unroll
                for (int dt = 0; dt < 4; ++dt)
                    #pragma unroll
                    for (int r = 0; r < 4; ++r) o[dt][r] *= rs4[r];
            }
            short8 pa = *(short8*)(&Ps[w][cl][g << 3]);
            #pragma unroll
            for (int dt = 0; dt < 4; ++dt)
                o[dt] = __builtin_amdgcn_mfma_f32_16x16x32_bf16(pa, vf[dt], o[dt], 0, 0, 0);
            if (jn < nkv) LOADV(jn);
        }
    }
#undef LOADK
#undef LOADV

    lsp += __shfl_xor(lsp, 16);
    lsp += __shfl_xor(lsp, 32);
    if (g == 0) { Cm[w][cl] = m; Cls[w][cl] = lsp; }
    #pragma unroll
    for (int dt = 0; dt < 4; ++dt)
        #pragma unroll
        for (int r = 0; r < 4; ++r)
            Co[w][(g << 2) + r][(dt << 4) + cl] = o[dt][r];
    __syncthreads();

    if (w == 0) {
        #pragma unroll
        for (int r = 0; r < 4; ++r) {
            const int row = (g << 2) + r;
            float M = fmaxf(fmaxf(Cm[0][row], Cm[1][row]), fmaxf(Cm[2][row], Cm[3][row]));
            float e0 = __expf(Cm[0][row] - M), e1 = __expf(Cm[1][row] - M);
            float e2 = __expf(Cm[2][row] - M), e3 = __expf(Cm[3][row] - M);
            float L = Cls[0][row] * e0 + Cls[1][row] * e1 + Cls[2][row] * e2 + Cls[3][row] * e3;
            float inv = 1.f / L;
            #pragma unroll
            for (int dt = 0; dt < 4; ++dt) {
                int d = (dt << 4) + cl;
                float O = Co[0][row][d] * e0 + Co[1][row][d] * e1
                        + Co[2][row][d] * e2 + Co[3][row][d] * e3;
                outp[(rowb + qw + row) * ND + d] = O * inv;
            }
        }
    }
}

extern "C" void kernel_launch(void* const* d_in, const int* in_sizes, int n_in,
                              void* d_out, int out_size, void* d_ws, size_t ws_size,
                              hipStream_t stream) {
    const float* x  = (const float*)d_in[0];
    // d_in[1] = mask (int32 tril) -- causal structure known, unused
    const float* WQ = (const float*)d_in[2];
    const float* WK = (const float*)d_in[3];
    const float* WV = (const float*)d_in[4];

    const size_t need = 786432u + 5u * 2097152u;   // 11,272,192 B (proven available)
    if (ws_size < need) return;

    char* ws = (char*)d_ws;
    short* wtph = (short*)(ws);                                  // packed B frags, 384 KB
    short* wtpl = (short*)(ws + 393216);
    short* qhi  = (short*)(ws + 786432);                         // 2 MB each
    short* qlo  = (short*)(ws + 786432 + 1 * 2097152);
    short* kfph = (short*)(ws + 786432 + 2 * 2097152);           // K frag-packed hi
    short* kfpl = (short*)(ws + 786432 + 3 * 2097152);           // K frag-packed lo
    short* vfp  = (short*)(ws + 786432 + 4 * 2097152);           // V frag-packed

    prep_wt<<<768, 256, 0, stream>>>(WQ, WK, WV, wtph, wtpl);
    proj_rope<<<512, 256, 0, stream>>>(x, wtph, wtpl, qhi, qlo, kfph, kfpl, vfp);
    attn_fused<<<1024, 256, 0, stream>>>(qhi, qlo, kfph, kfpl, vfp, (float*)d_out);
}